// Round 11
// baseline (436.769 us; speedup 1.0000x reference)
//
#include <hip/hip_runtime.h>
#include <hip/hip_bf16.h>
#include <stdint.h>

typedef __bf16 bf16_t;
typedef __bf16 bf16x8 __attribute__((ext_vector_type(8)));
typedef __bf16 bf16x4 __attribute__((ext_vector_type(4)));
typedef float f32x4 __attribute__((ext_vector_type(4)));

#define NFEAT 256   // feature dim (both layers)
#define KDIM  512   // concat K = 2*NFEAT
#define BM 64
#define BN 128
#define BK 64
#define NBB 640     // k_graph grid (co-resident: 4 waves/block, cap 2048 blocks)

__device__ __forceinline__ void gload_lds16(const void* g, void* l) {
  __builtin_amdgcn_global_load_lds(
      (const __attribute__((address_space(1))) unsigned int*)g,
      (__attribute__((address_space(3))) unsigned int*)l, 16, 0, 0);
}

// zero-initialized at module load; every replay leaves them zeroed again
__device__ int g_bar[4];
__device__ int g_done;
__device__ int g_part[128];

// device-wide barrier: all threads fence, 1 arrival/block, throttled spin.
__device__ __forceinline__ void grid_bar(int idx, int nbB) {
  __threadfence();
  __syncthreads();
  if (threadIdx.x == 0) {
    atomicAdd(&g_bar[idx], 1);
    while (atomicAdd(&g_bar[idx], 0) < nbB) __builtin_amdgcn_s_sleep(2);
  }
  __syncthreads();
}

// ---------------- mega graph-prep: prep + count + scan + scatter ------------
// NBB co-resident blocks. Scan chunks handled by blocks 0..nbS-1 only.
__global__ __launch_bounds__(256) void k_graph(
    const float* __restrict__ F,
    const float* __restrict__ Ws1, const float* __restrict__ Wn1,
    const float* __restrict__ Ws2, const float* __restrict__ Wn2,
    bf16_t* __restrict__ WT1, bf16_t* __restrict__ WT2,
    bf16_t* __restrict__ X,
    const int* __restrict__ src, const int* __restrict__ dst,
    int* __restrict__ deg, int* __restrict__ offsets, int* __restrict__ cursor,
    float* __restrict__ inv_deg, int* __restrict__ csr_src, int2* __restrict__ epack,
    int nNodes, int mpad, int nE, int nbS) {
  const int b   = blockIdx.x;
  const int tid = threadIdx.x;
  const int gt  = b * 256 + tid;
  const int G   = NBB * 256;

  // ---- phase 0: prep (deg=0, weights->bf16, features->bf16) ----
  for (int t = gt; t < mpad; t += G) atomicExch(&deg[t], 0);
  for (int t = gt; t < 2 * NFEAT * KDIM; t += G) {
    int layer = t >> 17;
    int r = t & (NFEAT * KDIM - 1);
    int n = r >> 9;
    int k = r & 511;
    const float* Ws = layer ? Ws2 : Ws1;
    const float* Wn = layer ? Wn2 : Wn1;
    float v = (k < NFEAT) ? Ws[k * NFEAT + n] : Wn[(k - NFEAT) * NFEAT + n];
    (layer ? WT2 : WT1)[r] = (bf16_t)v;
  }
  for (int t = gt; t < mpad * 64; t += G) {
    int n = t >> 6;
    int c = (t & 63) * 4;
    float4 v = make_float4(0.f, 0.f, 0.f, 0.f);
    if (n < nNodes) v = *(const float4*)&F[(size_t)n * NFEAT + c];
    bf16x4 o;
    o[0] = (bf16_t)v.x; o[1] = (bf16_t)v.y; o[2] = (bf16_t)v.z; o[3] = (bf16_t)v.w;
    *(bf16x4*)&X[(size_t)n * KDIM + c] = o;
  }
  grid_bar(0, NBB);

  // ---- phase 1: degree count ----
  for (int e = gt; e < nE; e += G) atomicAdd(&deg[dst[e]], 1);
  grid_bar(1, NBB);

  // ---- phase 2a: local scan of 256-node chunk (blocks 0..nbS-1) ----
  __shared__ int s[256], p[256];
  int d = 0;
  if (b < nbS) {
    const int i = b * 256 + tid;
    d = (i < mpad) ? atomicAdd(&deg[i], 0) : 0;
    s[tid] = d;
    __syncthreads();
    for (int off = 1; off < 256; off <<= 1) {
      int v = (tid >= off) ? s[tid - off] : 0;
      __syncthreads();
      s[tid] += v;
      __syncthreads();
    }
    if (tid == 255) atomicExch(&g_part[b], s[255]);
  }
  grid_bar(2, NBB);

  // ---- phase 2b: block prefix + write offsets/cursor/inv_deg ----
  if (b < nbS) {
    int pv = 0;
    if (tid < b) pv = atomicAdd(&g_part[tid], 0);
    p[tid] = pv;
    __syncthreads();
    for (int off = 128; off; off >>= 1) {
      if (tid < off) p[tid] += p[tid + off];
      __syncthreads();
    }
    const int i = b * 256 + tid;
    if (i < mpad) {
      int excl = p[0] + s[tid] - d;
      offsets[i] = excl;
      atomicExch(&cursor[i], excl);
      inv_deg[i] = 1.0f / (float)(d > 1 ? d : 1);
    }
  }
  grid_bar(3, NBB);

  // ---- phase 3: scatter ----
  for (int e = gt; e < nE; e += G) {
    int dd = dst[e];
    int ss = src[e];
    int pos = atomicAdd(&cursor[dd], 1);
    csr_src[pos] = ss;
    epack[pos] = make_int2((dd << 16) | ss, e);
  }

  // ---- departure: last block resets counters for next replay ----
  __syncthreads();
  if (tid == 0) {
    int old = atomicAdd(&g_done, 1);
    if (old == NBB - 1) {
      atomicExch(&g_bar[0], 0);
      atomicExch(&g_bar[1], 0);
      atomicExch(&g_bar[2], 0);
      atomicExch(&g_bar[3], 0);
      atomicExch(&g_done, 0);
    }
  }
}

// ---------------- aggregation (gather-mean) ----------------
// half-wave (32 lanes) per node; lane owns 8 cols (16B loads).
// 4 independent row loads in flight; indices prefetched one batch ahead.
__global__ __launch_bounds__(256) void k_agg(const bf16_t* __restrict__ Hin,
                                             bf16_t* __restrict__ Hout,
                                             const int* __restrict__ csr_src,
                                             const int* __restrict__ offsets,
                                             const int* __restrict__ deg,
                                             const float* __restrict__ inv_deg,
                                             int instride, int outstride) {
  const int n   = blockIdx.x * 8 + (threadIdx.x >> 5);
  const int l32 = threadIdx.x & 31;
  const int beg = offsets[n];
  const int cnt = deg[n];
  const size_t colo = (size_t)l32 * 8;

  float acc[8] = {0.f, 0.f, 0.f, 0.f, 0.f, 0.f, 0.f, 0.f};

  int s[4];
  #pragma unroll
  for (int q = 0; q < 4; ++q) s[q] = (q < cnt) ? csr_src[beg + q] : -1;

  for (int i = 0; i < cnt; i += 4) {
    bf16x8 v[4];
    bool h[4];
    #pragma unroll
    for (int q = 0; q < 4; ++q) {
      h[q] = (s[q] >= 0);
      if (h[q]) v[q] = *(const bf16x8*)&Hin[(size_t)s[q] * instride + colo];
    }
    #pragma unroll
    for (int q = 0; q < 4; ++q) {
      int j = i + 4 + q;
      s[q] = (j < cnt) ? csr_src[beg + j] : -1;
    }
    #pragma unroll
    for (int q = 0; q < 4; ++q) {
      if (h[q]) {
        #pragma unroll
        for (int e = 0; e < 8; ++e) acc[e] += (float)v[q][e];
      }
    }
  }

  float w = inv_deg[n];
  bf16x8 o;
  #pragma unroll
  for (int e = 0; e < 8; ++e) o[e] = (bf16_t)(acc[e] * w);
  *(bf16x8*)&Hout[(size_t)n * outstride + NFEAT + colo] = o;
}

// ---------------- GEMM: [mpad x 512] @ [512 x 256] -> bf16 out ----------------
__global__ __launch_bounds__(256, 3) void k_gemm(const bf16_t* __restrict__ A,
                                                 const bf16_t* __restrict__ BT,
                                                 const float* __restrict__ bias,
                                                 bf16_t* __restrict__ Cout,
                                                 int ostride, int relu) {
  __shared__ __align__(16) bf16_t As[2][BM * BK];
  __shared__ __align__(16) bf16_t Bs[2][BN * BK];
  const int tid  = threadIdx.x;
  const int lane = tid & 63;
  const int wave = tid >> 6;
  const int wr = wave >> 1, wc = wave & 1;    // 2x2 waves, 32x64 each
  const int m0 = blockIdx.x * BM;
  const int n0 = blockIdx.y * BN;
  const int l15 = lane & 15;
  const int lk8 = (lane >> 4) * 8;

  f32x4 acc[2][4] = {};

  auto stage = [&](int buf, int kt) {
    const int k0 = kt * BK;
    #pragma unroll
    for (int i = 0; i < 2; ++i) {          // A: 64x64 = 512 chunks
      int idx = i * 256 + tid;
      int row = idx >> 3;
      int c8  = (idx & 7) * 8;
      gload_lds16(A + (size_t)(m0 + row) * KDIM + k0 + c8,
                  (char*)&As[buf][0] + (i * 256 + wave * 64) * 16);
    }
    #pragma unroll
    for (int i = 0; i < 4; ++i) {          // B: 128x64 = 1024 chunks
      int idx = i * 256 + tid;
      int row = idx >> 3;
      int c8  = (idx & 7) * 8;
      gload_lds16(BT + (size_t)(n0 + row) * KDIM + k0 + c8,
                  (char*)&Bs[buf][0] + (i * 256 + wave * 64) * 16);
    }
  };

  auto compute = [&](int buf) {
    #pragma unroll
    for (int kk = 0; kk < 2; ++kk) {
      bf16x8 af[2], bfr[4];
      #pragma unroll
      for (int m = 0; m < 2; ++m) {
        int row = wr * 32 + m * 16 + l15;
        af[m] = *(const bf16x8*)&As[buf][row * BK + kk * 32 + lk8];
      }
      #pragma unroll
      for (int n = 0; n < 4; ++n) {
        int col = wc * 64 + n * 16 + l15;
        bfr[n] = *(const bf16x8*)&Bs[buf][col * BK + kk * 32 + lk8];
      }
      #pragma unroll
      for (int m = 0; m < 2; ++m)
        #pragma unroll
        for (int n = 0; n < 4; ++n)
          acc[m][n] = __builtin_amdgcn_mfma_f32_16x16x32_bf16(af[m], bfr[n], acc[m][n], 0, 0, 0);
    }
  };

  stage(0, 0);
  __syncthreads();
  const int nt = KDIM / BK;   // 8
  int cur = 0;
  for (int t = 0; t < nt; ++t) {
    if (t + 1 < nt) stage(cur ^ 1, t + 1);
    compute(cur);
    __syncthreads();
    cur ^= 1;
  }

  #pragma unroll
  for (int n = 0; n < 4; ++n) {
    int col = n0 + wc * 64 + n * 16 + l15;
    float bv = bias[col];
    #pragma unroll
    for (int m = 0; m < 2; ++m) {
      int rbase = m0 + wr * 32 + m * 16 + (lane >> 4) * 4;
      #pragma unroll
      for (int j = 0; j < 4; ++j) {
        float v = acc[m][n][j] + bv;
        if (relu) v = fmaxf(v, 0.f);
        Cout[(size_t)(rbase + j) * ostride + col] = (bf16_t)v;
      }
    }
  }
}

// ---------------- per-edge dot via MFMA, CSR (dst-sorted) order -------------
__global__ __launch_bounds__(256) void k_edge_dot(const bf16_t* __restrict__ H,
                                                  const int2* __restrict__ epack,
                                                  float* __restrict__ out, int nE) {
  const int wid  = (blockIdx.x * blockDim.x + threadIdx.x) >> 6;
  const int lane = threadIdx.x & 63;
  const int l15  = lane & 15;
  const int hi   = lane >> 4;
  const int e0   = wid * 16;
  if (e0 >= nE) return;
  int pos = e0 + l15;
  if (pos >= nE) pos = nE - 1;        // clamp (loads only; store guarded)

  const int2 e = epack[pos];
  const int s = e.x & 0xFFFF;
  const int d = ((unsigned)e.x) >> 16;
  const bf16_t* ps = H + (size_t)s * NFEAT + hi * 8;
  const bf16_t* pd = H + (size_t)d * NFEAT + hi * 8;

  f32x4 acc = {0.f, 0.f, 0.f, 0.f};
  #pragma unroll
  for (int ks = 0; ks < 8; ++ks) {
    bf16x8 a = *(const bf16x8*)(ps + ks * 32);
    bf16x8 b = *(const bf16x8*)(pd + ks * 32);
    acc = __builtin_amdgcn_mfma_f32_16x16x32_bf16(a, b, acc, 0, 0, 0);
  }

  if ((l15 >> 2) == hi && (e0 + l15) < nE) {
    int j = l15 & 3;
    float v = acc[0];
    v = (j == 1) ? acc[1] : v;
    v = (j == 2) ? acc[2] : v;
    v = (j == 3) ? acc[3] : v;
    out[e.y] = v;
  }
}

// ---------------- launcher ----------------

extern "C" void kernel_launch(void* const* d_in, const int* in_sizes, int n_in,
                              void* d_out, int out_size, void* d_ws, size_t ws_size,
                              hipStream_t stream) {
  const float* features = (const float*)d_in[0];
  const int*   src      = (const int*)d_in[1];
  const int*   dst      = (const int*)d_in[2];
  const float* Wself1   = (const float*)d_in[3];
  const float* Wneigh1  = (const float*)d_in[4];
  const float* b1       = (const float*)d_in[5];
  const float* Wself2   = (const float*)d_in[6];
  const float* Wneigh2  = (const float*)d_in[7];
  const float* b2       = (const float*)d_in[8];
  float* score = (float*)d_out;

  const int nNodes = in_sizes[0] / NFEAT;       // 20000
  const int nE     = in_sizes[1];               // 320000
  const int mpad   = ((nNodes + 127) / 128) * 128;  // 20096

  char* ws = (char*)d_ws;
  size_t off = 0;
  auto alloc = [&](size_t bytes) { char* p = ws + off; off += (bytes + 255) & ~(size_t)255; return p; };
  bf16_t* Xcat1   = (bf16_t*)alloc((size_t)mpad * KDIM * 2);
  bf16_t* Xcat2   = (bf16_t*)alloc((size_t)mpad * KDIM * 2);
  bf16_t* H2      = (bf16_t*)alloc((size_t)mpad * NFEAT * 2);
  bf16_t* WT1     = (bf16_t*)alloc((size_t)NFEAT * KDIM * 2);
  bf16_t* WT2     = (bf16_t*)alloc((size_t)NFEAT * KDIM * 2);
  int*    deg     = (int*)alloc((size_t)mpad * 4);
  int*    offsets = (int*)alloc((size_t)mpad * 4);
  int*    cursor  = (int*)alloc((size_t)mpad * 4);
  float*  inv_deg = (float*)alloc((size_t)mpad * 4);
  int*    csr_src = (int*)alloc((size_t)nE * 4);
  int2*   epack   = (int2*)alloc((size_t)nE * 8);

  const int nbS = (mpad + 255) / 256;    // 79 scan chunks

  // mega graph prep: prep + count + scan + scatter (one kernel, 4 barriers)
  k_graph<<<NBB, 256, 0, stream>>>(features, Wself1, Wneigh1, Wself2, Wneigh2,
                                   WT1, WT2, Xcat1, src, dst,
                                   deg, offsets, cursor, inv_deg, csr_src, epack,
                                   nNodes, mpad, nE, nbS);

  // layer 1
  k_agg<<<mpad / 8, 256, 0, stream>>>(Xcat1, Xcat1, csr_src, offsets, deg, inv_deg, KDIM, KDIM);
  dim3 ggrid(mpad / BM, NFEAT / BN);
  k_gemm<<<ggrid, 256, 0, stream>>>(Xcat1, WT1, b1, Xcat2, KDIM, 1);

  // layer 2
  k_agg<<<mpad / 8, 256, 0, stream>>>(Xcat2, Xcat2, csr_src, offsets, deg, inv_deg, KDIM, KDIM);
  k_gemm<<<ggrid, 256, 0, stream>>>(Xcat2, WT2, b2, H2, NFEAT, 0);

  // edge scores: one wave per 16 CSR slots
  const int nWaves = (nE + 15) / 16;
  k_edge_dot<<<(nWaves + 3) / 4, 256, 0, stream>>>(H2, epack, score, nE);
}

// Round 12
// 153.257 us; speedup vs baseline: 2.8499x; 2.8499x over previous
//
#include <hip/hip_runtime.h>
#include <hip/hip_bf16.h>
#include <stdint.h>

typedef __bf16 bf16_t;
typedef __bf16 bf16x8 __attribute__((ext_vector_type(8)));
typedef __bf16 bf16x4 __attribute__((ext_vector_type(4)));
typedef float f32x4 __attribute__((ext_vector_type(4)));

#define NFEAT 256   // feature dim (both layers)
#define KDIM  512   // concat K = 2*NFEAT
#define BM 64
#define BN 128
#define BK 64

__device__ __forceinline__ void gload_lds16(const void* g, void* l) {
  __builtin_amdgcn_global_load_lds(
      (const __attribute__((address_space(1))) unsigned int*)g,
      (__attribute__((address_space(3))) unsigned int*)l, 16, 0, 0);
}

// ---------------- graph prep ----------------

__global__ void k_count_deg(const int* __restrict__ dst, int* __restrict__ deg, int nE) {
  int i = blockIdx.x * blockDim.x + threadIdx.x;
  if (i < nE) atomicAdd(&deg[dst[i]], 1);
}

// block sums: partial[b] = sum(deg[b*256 .. b*256+255])
__global__ __launch_bounds__(256) void k_scan_part(const int* __restrict__ deg,
                                                   int* __restrict__ partial, int n) {
  const int tid = threadIdx.x;
  int i = blockIdx.x * 256 + tid;
  int d = (i < n) ? deg[i] : 0;
  #pragma unroll
  for (int off = 32; off; off >>= 1) d += __shfl_xor(d, off, 64);
  __shared__ int ws[4];
  if ((tid & 63) == 0) ws[tid >> 6] = d;
  __syncthreads();
  if (tid == 0) partial[blockIdx.x] = ws[0] + ws[1] + ws[2] + ws[3];
}

// merged mid+final: each block scans the <=256 partials itself, then local scan
__global__ __launch_bounds__(256) void k_scan_final(const int* __restrict__ deg,
                                                    const int* __restrict__ partial,
                                                    int* __restrict__ offsets,
                                                    int* __restrict__ cursor,
                                                    float* __restrict__ inv_deg,
                                                    int n, int nb) {
  __shared__ int s[256], p[256];
  const int tid = threadIdx.x;
  // inclusive scan of partials in p[]
  int pv = (tid < nb) ? partial[tid] : 0;
  p[tid] = pv;
  __syncthreads();
  for (int off = 1; off < 256; off <<= 1) {
    int v = (tid >= off) ? p[tid - off] : 0;
    __syncthreads();
    p[tid] += v;
    __syncthreads();
  }
  // local scan of this block's 256 degrees
  int i = blockIdx.x * 256 + tid;
  int d = (i < n) ? deg[i] : 0;
  s[tid] = d;
  __syncthreads();
  for (int off = 1; off < 256; off <<= 1) {
    int v = (tid >= off) ? s[tid - off] : 0;
    __syncthreads();
    s[tid] += v;
    __syncthreads();
  }
  if (i < n) {
    int block_excl = p[blockIdx.x] - partial[blockIdx.x];
    int excl = block_excl + s[tid] - d;
    offsets[i] = excl;
    cursor[i]  = excl;
    inv_deg[i] = 1.0f / (float)(d > 1 ? d : 1);
  }
}

// writes dense csr_src (4B, for agg) and packed {dst<<16|src, eid} (8B)
__global__ void k_scatter(const int* __restrict__ src, const int* __restrict__ dst,
                          int* __restrict__ cursor, int* __restrict__ csr_src,
                          int2* __restrict__ epack, int nE) {
  int i = blockIdx.x * blockDim.x + threadIdx.x;
  if (i < nE) {
    int d = dst[i];
    int s = src[i];
    int pos = atomicAdd(&cursor[d], 1);
    csr_src[pos] = s;
    epack[pos] = make_int2((d << 16) | s, i);
  }
}

// ---------------- fused prep: weights->bf16 WT, features->bf16 X, deg=0 -----
// X is the concat buffer [mpad][512]; features go into cols 0..255.
__global__ void k_prep(const float* __restrict__ F,
                       const float* __restrict__ Ws1, const float* __restrict__ Wn1,
                       const float* __restrict__ Ws2, const float* __restrict__ Wn2,
                       bf16_t* __restrict__ WT1, bf16_t* __restrict__ WT2,
                       bf16_t* __restrict__ X,
                       int* __restrict__ deg, int nNodes, int mpad) {
  int t = blockIdx.x * blockDim.x + threadIdx.x;
  if (t < mpad) deg[t] = 0;
  if (t < 2 * NFEAT * KDIM) {
    int layer = t >> 17;
    int r = t & (NFEAT * KDIM - 1);
    int n = r >> 9;
    int k = r & 511;
    const float* Ws = layer ? Ws2 : Ws1;
    const float* Wn = layer ? Wn2 : Wn1;
    float v = (k < NFEAT) ? Ws[k * NFEAT + n] : Wn[(k - NFEAT) * NFEAT + n];
    (layer ? WT2 : WT1)[r] = (bf16_t)v;
  }
  int n = t >> 6;
  int c = (t & 63) * 4;
  if (n < mpad) {
    float4 v = make_float4(0.f, 0.f, 0.f, 0.f);
    if (n < nNodes) v = *(const float4*)&F[(size_t)n * NFEAT + c];
    bf16x4 o;
    o[0] = (bf16_t)v.x; o[1] = (bf16_t)v.y; o[2] = (bf16_t)v.z; o[3] = (bf16_t)v.w;
    *(bf16x4*)&X[(size_t)n * KDIM + c] = o;
  }
}

// ---------------- aggregation (gather-mean) ----------------
// half-wave (32 lanes) per node; lane owns 8 cols (16B loads).
// 4 independent row loads in flight; indices prefetched one batch ahead.
__global__ __launch_bounds__(256) void k_agg(const bf16_t* __restrict__ Hin,
                                             bf16_t* __restrict__ Hout,
                                             const int* __restrict__ csr_src,
                                             const int* __restrict__ offsets,
                                             const int* __restrict__ deg,
                                             const float* __restrict__ inv_deg,
                                             int instride, int outstride) {
  const int n   = blockIdx.x * 8 + (threadIdx.x >> 5);
  const int l32 = threadIdx.x & 31;
  const int beg = offsets[n];
  const int cnt = deg[n];
  const size_t colo = (size_t)l32 * 8;

  float acc[8] = {0.f, 0.f, 0.f, 0.f, 0.f, 0.f, 0.f, 0.f};

  int s[4];
  #pragma unroll
  for (int q = 0; q < 4; ++q) s[q] = (q < cnt) ? csr_src[beg + q] : -1;

  for (int i = 0; i < cnt; i += 4) {
    bf16x8 v[4];
    bool h[4];
    #pragma unroll
    for (int q = 0; q < 4; ++q) {
      h[q] = (s[q] >= 0);
      if (h[q]) v[q] = *(const bf16x8*)&Hin[(size_t)s[q] * instride + colo];
    }
    #pragma unroll
    for (int q = 0; q < 4; ++q) {
      int j = i + 4 + q;
      s[q] = (j < cnt) ? csr_src[beg + j] : -1;
    }
    #pragma unroll
    for (int q = 0; q < 4; ++q) {
      if (h[q]) {
        #pragma unroll
        for (int e = 0; e < 8; ++e) acc[e] += (float)v[q][e];
      }
    }
  }

  float w = inv_deg[n];
  bf16x8 o;
  #pragma unroll
  for (int e = 0; e < 8; ++e) o[e] = (bf16_t)(acc[e] * w);
  *(bf16x8*)&Hout[(size_t)n * outstride + NFEAT + colo] = o;
}

// ---------------- GEMM: [mpad x 512] @ [512 x 256] -> bf16 out ----------------
__global__ __launch_bounds__(256, 3) void k_gemm(const bf16_t* __restrict__ A,
                                                 const bf16_t* __restrict__ BT,
                                                 const float* __restrict__ bias,
                                                 bf16_t* __restrict__ Cout,
                                                 int ostride, int relu) {
  __shared__ __align__(16) bf16_t As[2][BM * BK];
  __shared__ __align__(16) bf16_t Bs[2][BN * BK];
  const int tid  = threadIdx.x;
  const int lane = tid & 63;
  const int wave = tid >> 6;
  const int wr = wave >> 1, wc = wave & 1;    // 2x2 waves, 32x64 each
  const int m0 = blockIdx.x * BM;
  const int n0 = blockIdx.y * BN;
  const int l15 = lane & 15;
  const int lk8 = (lane >> 4) * 8;

  f32x4 acc[2][4] = {};

  auto stage = [&](int buf, int kt) {
    const int k0 = kt * BK;
    #pragma unroll
    for (int i = 0; i < 2; ++i) {          // A: 64x64 = 512 chunks
      int idx = i * 256 + tid;
      int row = idx >> 3;
      int c8  = (idx & 7) * 8;
      gload_lds16(A + (size_t)(m0 + row) * KDIM + k0 + c8,
                  (char*)&As[buf][0] + (i * 256 + wave * 64) * 16);
    }
    #pragma unroll
    for (int i = 0; i < 4; ++i) {          // B: 128x64 = 1024 chunks
      int idx = i * 256 + tid;
      int row = idx >> 3;
      int c8  = (idx & 7) * 8;
      gload_lds16(BT + (size_t)(n0 + row) * KDIM + k0 + c8,
                  (char*)&Bs[buf][0] + (i * 256 + wave * 64) * 16);
    }
  };

  auto compute = [&](int buf) {
    #pragma unroll
    for (int kk = 0; kk < 2; ++kk) {
      bf16x8 af[2], bfr[4];
      #pragma unroll
      for (int m = 0; m < 2; ++m) {
        int row = wr * 32 + m * 16 + l15;
        af[m] = *(const bf16x8*)&As[buf][row * BK + kk * 32 + lk8];
      }
      #pragma unroll
      for (int n = 0; n < 4; ++n) {
        int col = wc * 64 + n * 16 + l15;
        bfr[n] = *(const bf16x8*)&Bs[buf][col * BK + kk * 32 + lk8];
      }
      #pragma unroll
      for (int m = 0; m < 2; ++m)
        #pragma unroll
        for (int n = 0; n < 4; ++n)
          acc[m][n] = __builtin_amdgcn_mfma_f32_16x16x32_bf16(af[m], bfr[n], acc[m][n], 0, 0, 0);
    }
  };

  stage(0, 0);
  __syncthreads();
  const int nt = KDIM / BK;   // 8
  int cur = 0;
  for (int t = 0; t < nt; ++t) {
    if (t + 1 < nt) stage(cur ^ 1, t + 1);
    compute(cur);
    __syncthreads();
    cur ^= 1;
  }

  #pragma unroll
  for (int n = 0; n < 4; ++n) {
    int col = n0 + wc * 64 + n * 16 + l15;
    float bv = bias[col];
    #pragma unroll
    for (int m = 0; m < 2; ++m) {
      int rbase = m0 + wr * 32 + m * 16 + (lane >> 4) * 4;
      #pragma unroll
      for (int j = 0; j < 4; ++j) {
        float v = acc[m][n][j] + bv;
        if (relu) v = fmaxf(v, 0.f);
        Cout[(size_t)(rbase + j) * ostride + col] = (bf16_t)v;
      }
    }
  }
}

// ---------------- per-edge dot via MFMA, CSR (dst-sorted) order -------------
__global__ __launch_bounds__(256) void k_edge_dot(const bf16_t* __restrict__ H,
                                                  const int2* __restrict__ epack,
                                                  float* __restrict__ out, int nE) {
  const int wid  = (blockIdx.x * blockDim.x + threadIdx.x) >> 6;
  const int lane = threadIdx.x & 63;
  const int l15  = lane & 15;
  const int hi   = lane >> 4;
  const int e0   = wid * 16;
  if (e0 >= nE) return;
  int pos = e0 + l15;
  if (pos >= nE) pos = nE - 1;        // clamp (loads only; store guarded)

  const int2 e = epack[pos];
  const int s = e.x & 0xFFFF;
  const int d = ((unsigned)e.x) >> 16;
  const bf16_t* ps = H + (size_t)s * NFEAT + hi * 8;
  const bf16_t* pd = H + (size_t)d * NFEAT + hi * 8;

  f32x4 acc = {0.f, 0.f, 0.f, 0.f};
  #pragma unroll
  for (int ks = 0; ks < 8; ++ks) {
    bf16x8 a = *(const bf16x8*)(ps + ks * 32);
    bf16x8 b = *(const bf16x8*)(pd + ks * 32);
    acc = __builtin_amdgcn_mfma_f32_16x16x32_bf16(a, b, acc, 0, 0, 0);
  }

  if ((l15 >> 2) == hi && (e0 + l15) < nE) {
    int j = l15 & 3;
    float v = acc[0];
    v = (j == 1) ? acc[1] : v;
    v = (j == 2) ? acc[2] : v;
    v = (j == 3) ? acc[3] : v;
    out[e.y] = v;
  }
}

// ---------------- launcher ----------------

extern "C" void kernel_launch(void* const* d_in, const int* in_sizes, int n_in,
                              void* d_out, int out_size, void* d_ws, size_t ws_size,
                              hipStream_t stream) {
  const float* features = (const float*)d_in[0];
  const int*   src      = (const int*)d_in[1];
  const int*   dst      = (const int*)d_in[2];
  const float* Wself1   = (const float*)d_in[3];
  const float* Wneigh1  = (const float*)d_in[4];
  const float* b1       = (const float*)d_in[5];
  const float* Wself2   = (const float*)d_in[6];
  const float* Wneigh2  = (const float*)d_in[7];
  const float* b2       = (const float*)d_in[8];
  float* score = (float*)d_out;

  const int nNodes = in_sizes[0] / NFEAT;       // 20000
  const int nE     = in_sizes[1];               // 320000
  const int mpad   = ((nNodes + 127) / 128) * 128;  // 20096

  char* ws = (char*)d_ws;
  size_t off = 0;
  auto alloc = [&](size_t bytes) { char* p = ws + off; off += (bytes + 255) & ~(size_t)255; return p; };
  bf16_t* Xcat1   = (bf16_t*)alloc((size_t)mpad * KDIM * 2);
  bf16_t* Xcat2   = (bf16_t*)alloc((size_t)mpad * KDIM * 2);
  bf16_t* H2      = (bf16_t*)alloc((size_t)mpad * NFEAT * 2);
  bf16_t* WT1     = (bf16_t*)alloc((size_t)NFEAT * KDIM * 2);
  bf16_t* WT2     = (bf16_t*)alloc((size_t)NFEAT * KDIM * 2);
  int*    deg     = (int*)alloc((size_t)mpad * 4);
  int*    offsets = (int*)alloc((size_t)mpad * 4);
  int*    cursor  = (int*)alloc((size_t)mpad * 4);
  float*  inv_deg = (float*)alloc((size_t)mpad * 4);
  int*    csr_src = (int*)alloc((size_t)nE * 4);
  int2*   epack   = (int2*)alloc((size_t)nE * 8);
  int*    partial = (int*)alloc(1024 * 4);

  const int eb = (nE + 255) / 256;
  const int nb = (mpad + 255) / 256;     // 79 scan blocks

  // fused prep (weights, features, deg=0) — must precede k_count_deg
  k_prep<<<(mpad * 64 + 255) / 256, 256, 0, stream>>>(features, Wself1, Wneigh1,
                                                      Wself2, Wneigh2, WT1, WT2,
                                                      Xcat1, deg, nNodes, mpad);

  // graph prep
  k_count_deg<<<eb, 256, 0, stream>>>(dst, deg, nE);
  k_scan_part<<<nb, 256, 0, stream>>>(deg, partial, mpad);
  k_scan_final<<<nb, 256, 0, stream>>>(deg, partial, offsets, cursor, inv_deg, mpad, nb);
  k_scatter<<<eb, 256, 0, stream>>>(src, dst, cursor, csr_src, epack, nE);

  // layer 1
  k_agg<<<mpad / 8, 256, 0, stream>>>(Xcat1, Xcat1, csr_src, offsets, deg, inv_deg, KDIM, KDIM);
  dim3 ggrid(mpad / BM, NFEAT / BN);
  k_gemm<<<ggrid, 256, 0, stream>>>(Xcat1, WT1, b1, Xcat2, KDIM, 1);

  // layer 2
  k_agg<<<mpad / 8, 256, 0, stream>>>(Xcat2, Xcat2, csr_src, offsets, deg, inv_deg, KDIM, KDIM);
  k_gemm<<<ggrid, 256, 0, stream>>>(Xcat2, WT2, b2, H2, NFEAT, 0);

  // edge scores: one wave per 16 CSR slots
  const int nWaves = (nE + 15) / 16;
  k_edge_dot<<<(nWaves + 3) / 4, 256, 0, stream>>>(H2, epack, score, nE);
}

// Round 13
// 152.736 us; speedup vs baseline: 2.8596x; 1.0034x over previous
//
#include <hip/hip_runtime.h>
#include <hip/hip_bf16.h>
#include <stdint.h>

typedef __bf16 bf16_t;
typedef __bf16 bf16x8 __attribute__((ext_vector_type(8)));
typedef __bf16 bf16x4 __attribute__((ext_vector_type(4)));
typedef float f32x4 __attribute__((ext_vector_type(4)));

#define NFEAT 256   // feature dim (both layers)
#define KDIM  512   // concat K = 2*NFEAT
#define BM 64
#define BN 128
#define BK 64

__device__ __forceinline__ void gload_lds16(const void* g, void* l) {
  __builtin_amdgcn_global_load_lds(
      (const __attribute__((address_space(1))) unsigned int*)g,
      (__attribute__((address_space(3))) unsigned int*)l, 16, 0, 0);
}

// ---------------- graph prep ----------------

__global__ void k_count_deg(const int* __restrict__ dst, int* __restrict__ deg, int nE) {
  int i = blockIdx.x * blockDim.x + threadIdx.x;
  if (i < nE) atomicAdd(&deg[dst[i]], 1);
}

// single-launch scan, no cross-block comm: block b sums its predecessor
// chunks itself (thread t<b sums chunk t via int4), then local scan.
__global__ __launch_bounds__(256) void k_scan(const int* __restrict__ deg,
                                              int* __restrict__ offsets,
                                              int* __restrict__ cursor,
                                              float* __restrict__ inv_deg,
                                              int n, int nb) {
  __shared__ int p[256], s[256];
  const int b = blockIdx.x;
  const int tid = threadIdx.x;

  // predecessor chunk sums (chunks 0..b-1 are fully in-bounds: b <= nb-1)
  int csum = 0;
  if (tid < b) {
    const int4* q = (const int4*)(deg + tid * 256);
    #pragma unroll 8
    for (int j = 0; j < 64; ++j) {
      int4 v = q[j];
      csum += v.x + v.y + v.z + v.w;
    }
  }
  p[tid] = csum;
  __syncthreads();
  for (int off = 128; off; off >>= 1) {
    if (tid < off) p[tid] += p[tid + off];
    __syncthreads();
  }
  const int block_excl = p[0];

  // local inclusive scan of this block's chunk
  const int i = b * 256 + tid;
  const int d = (i < n) ? deg[i] : 0;
  s[tid] = d;
  __syncthreads();
  for (int off = 1; off < 256; off <<= 1) {
    int v = (tid >= off) ? s[tid - off] : 0;
    __syncthreads();
    s[tid] += v;
    __syncthreads();
  }
  if (i < n) {
    int excl = block_excl + s[tid] - d;
    offsets[i] = excl;
    cursor[i]  = excl;
    inv_deg[i] = 1.0f / (float)(d > 1 ? d : 1);
  }
}

// writes dense csr_src (4B, for agg) and packed {dst<<16|src, eid} (8B)
__global__ void k_scatter(const int* __restrict__ src, const int* __restrict__ dst,
                          int* __restrict__ cursor, int* __restrict__ csr_src,
                          int2* __restrict__ epack, int nE) {
  int i = blockIdx.x * blockDim.x + threadIdx.x;
  if (i < nE) {
    int d = dst[i];
    int s = src[i];
    int pos = atomicAdd(&cursor[d], 1);
    csr_src[pos] = s;
    epack[pos] = make_int2((d << 16) | s, i);
  }
}

// ---------------- fused prep ----------------
// blocks 0..63: coalesced LDS tile-transpose of the 4 weight matrices into
//   WT[l][n][k] (bf16). blk = layer*32 + half*16 + ti*4 + tj.
// blocks 64.. : features f32->bf16 into Xcat cols 0..255 + deg=0.
__global__ __launch_bounds__(256) void k_prep(
    const float* __restrict__ F,
    const float* __restrict__ Ws1, const float* __restrict__ Wn1,
    const float* __restrict__ Ws2, const float* __restrict__ Wn2,
    bf16_t* __restrict__ WT1, bf16_t* __restrict__ WT2,
    bf16_t* __restrict__ X,
    int* __restrict__ deg, int nNodes, int mpad) {
  const int blk = blockIdx.x;
  if (blk < 64) {
    __shared__ float tile[64][65];
    const int layer = blk >> 5;
    const int half  = (blk >> 4) & 1;
    const int ti    = (blk >> 2) & 3;   // k-tile
    const int tj    = blk & 3;          // n-tile
    const float* W = layer ? (half ? Wn2 : Ws2) : (half ? Wn1 : Ws1);
    bf16_t* WT = layer ? WT2 : WT1;
    const int c  = threadIdx.x & 63;
    const int r0 = threadIdx.x >> 6;    // 0..3
    const int k0 = ti * 64, n0 = tj * 64;
    #pragma unroll
    for (int j = 0; j < 16; ++j) {
      int r = r0 * 16 + j;
      tile[r][c] = W[(size_t)(k0 + r) * NFEAT + n0 + c];   // coalesced over c
    }
    __syncthreads();
    #pragma unroll
    for (int j = 0; j < 16; ++j) {
      int r = r0 * 16 + j;
      WT[(size_t)(n0 + r) * KDIM + half * NFEAT + k0 + c] = (bf16_t)tile[c][r];
    }
  } else {
    int t = (blk - 64) * 256 + threadIdx.x;
    if (t < mpad) deg[t] = 0;
    int n = t >> 6;
    int c = (t & 63) * 4;
    if (n < mpad) {
      float4 v = make_float4(0.f, 0.f, 0.f, 0.f);
      if (n < nNodes) v = *(const float4*)&F[(size_t)n * NFEAT + c];
      bf16x4 o;
      o[0] = (bf16_t)v.x; o[1] = (bf16_t)v.y; o[2] = (bf16_t)v.z; o[3] = (bf16_t)v.w;
      *(bf16x4*)&X[(size_t)n * KDIM + c] = o;
    }
  }
}

// ---------------- aggregation (gather-mean) ----------------
// half-wave (32 lanes) per node; lane owns 8 cols (16B loads).
// 4 independent row loads in flight; indices prefetched one batch ahead.
__global__ __launch_bounds__(256) void k_agg(const bf16_t* __restrict__ Hin,
                                             bf16_t* __restrict__ Hout,
                                             const int* __restrict__ csr_src,
                                             const int* __restrict__ offsets,
                                             const int* __restrict__ deg,
                                             const float* __restrict__ inv_deg,
                                             int instride, int outstride) {
  const int n   = blockIdx.x * 8 + (threadIdx.x >> 5);
  const int l32 = threadIdx.x & 31;
  const int beg = offsets[n];
  const int cnt = deg[n];
  const size_t colo = (size_t)l32 * 8;

  float acc[8] = {0.f, 0.f, 0.f, 0.f, 0.f, 0.f, 0.f, 0.f};

  int s[4];
  #pragma unroll
  for (int q = 0; q < 4; ++q) s[q] = (q < cnt) ? csr_src[beg + q] : -1;

  for (int i = 0; i < cnt; i += 4) {
    bf16x8 v[4];
    bool h[4];
    #pragma unroll
    for (int q = 0; q < 4; ++q) {
      h[q] = (s[q] >= 0);
      if (h[q]) v[q] = *(const bf16x8*)&Hin[(size_t)s[q] * instride + colo];
    }
    #pragma unroll
    for (int q = 0; q < 4; ++q) {
      int j = i + 4 + q;
      s[q] = (j < cnt) ? csr_src[beg + j] : -1;
    }
    #pragma unroll
    for (int q = 0; q < 4; ++q) {
      if (h[q]) {
        #pragma unroll
        for (int e = 0; e < 8; ++e) acc[e] += (float)v[q][e];
      }
    }
  }

  float w = inv_deg[n];
  bf16x8 o;
  #pragma unroll
  for (int e = 0; e < 8; ++e) o[e] = (bf16_t)(acc[e] * w);
  *(bf16x8*)&Hout[(size_t)n * outstride + NFEAT + colo] = o;
}

// ---------------- GEMM: [mpad x 512] @ [512 x 256] -> bf16 out ----------------
__global__ __launch_bounds__(256, 3) void k_gemm(const bf16_t* __restrict__ A,
                                                 const bf16_t* __restrict__ BT,
                                                 const float* __restrict__ bias,
                                                 bf16_t* __restrict__ Cout,
                                                 int ostride, int relu) {
  __shared__ __align__(16) bf16_t As[2][BM * BK];
  __shared__ __align__(16) bf16_t Bs[2][BN * BK];
  const int tid  = threadIdx.x;
  const int lane = tid & 63;
  const int wave = tid >> 6;
  const int wr = wave >> 1, wc = wave & 1;    // 2x2 waves, 32x64 each
  const int m0 = blockIdx.x * BM;
  const int n0 = blockIdx.y * BN;
  const int l15 = lane & 15;
  const int lk8 = (lane >> 4) * 8;

  f32x4 acc[2][4] = {};

  auto stage = [&](int buf, int kt) {
    const int k0 = kt * BK;
    #pragma unroll
    for (int i = 0; i < 2; ++i) {          // A: 64x64 = 512 chunks
      int idx = i * 256 + tid;
      int row = idx >> 3;
      int c8  = (idx & 7) * 8;
      gload_lds16(A + (size_t)(m0 + row) * KDIM + k0 + c8,
                  (char*)&As[buf][0] + (i * 256 + wave * 64) * 16);
    }
    #pragma unroll
    for (int i = 0; i < 4; ++i) {          // B: 128x64 = 1024 chunks
      int idx = i * 256 + tid;
      int row = idx >> 3;
      int c8  = (idx & 7) * 8;
      gload_lds16(BT + (size_t)(n0 + row) * KDIM + k0 + c8,
                  (char*)&Bs[buf][0] + (i * 256 + wave * 64) * 16);
    }
  };

  auto compute = [&](int buf) {
    #pragma unroll
    for (int kk = 0; kk < 2; ++kk) {
      bf16x8 af[2], bfr[4];
      #pragma unroll
      for (int m = 0; m < 2; ++m) {
        int row = wr * 32 + m * 16 + l15;
        af[m] = *(const bf16x8*)&As[buf][row * BK + kk * 32 + lk8];
      }
      #pragma unroll
      for (int n = 0; n < 4; ++n) {
        int col = wc * 64 + n * 16 + l15;
        bfr[n] = *(const bf16x8*)&Bs[buf][col * BK + kk * 32 + lk8];
      }
      #pragma unroll
      for (int m = 0; m < 2; ++m)
        #pragma unroll
        for (int n = 0; n < 4; ++n)
          acc[m][n] = __builtin_amdgcn_mfma_f32_16x16x32_bf16(af[m], bfr[n], acc[m][n], 0, 0, 0);
    }
  };

  stage(0, 0);
  __syncthreads();
  const int nt = KDIM / BK;   // 8
  int cur = 0;
  for (int t = 0; t < nt; ++t) {
    if (t + 1 < nt) stage(cur ^ 1, t + 1);
    compute(cur);
    __syncthreads();
    cur ^= 1;
  }

  #pragma unroll
  for (int n = 0; n < 4; ++n) {
    int col = n0 + wc * 64 + n * 16 + l15;
    float bv = bias[col];
    #pragma unroll
    for (int m = 0; m < 2; ++m) {
      int rbase = m0 + wr * 32 + m * 16 + (lane >> 4) * 4;
      #pragma unroll
      for (int j = 0; j < 4; ++j) {
        float v = acc[m][n][j] + bv;
        if (relu) v = fmaxf(v, 0.f);
        Cout[(size_t)(rbase + j) * ostride + col] = (bf16_t)v;
      }
    }
  }
}

// ---------------- per-edge dot via MFMA, CSR (dst-sorted) order -------------
__global__ __launch_bounds__(256) void k_edge_dot(const bf16_t* __restrict__ H,
                                                  const int2* __restrict__ epack,
                                                  float* __restrict__ out, int nE) {
  const int wid  = (blockIdx.x * blockDim.x + threadIdx.x) >> 6;
  const int lane = threadIdx.x & 63;
  const int l15  = lane & 15;
  const int hi   = lane >> 4;
  const int e0   = wid * 16;
  if (e0 >= nE) return;
  int pos = e0 + l15;
  if (pos >= nE) pos = nE - 1;        // clamp (loads only; store guarded)

  const int2 e = epack[pos];
  const int s = e.x & 0xFFFF;
  const int d = ((unsigned)e.x) >> 16;
  const bf16_t* ps = H + (size_t)s * NFEAT + hi * 8;
  const bf16_t* pd = H + (size_t)d * NFEAT + hi * 8;

  f32x4 acc = {0.f, 0.f, 0.f, 0.f};
  #pragma unroll
  for (int ks = 0; ks < 8; ++ks) {
    bf16x8 a = *(const bf16x8*)(ps + ks * 32);
    bf16x8 b = *(const bf16x8*)(pd + ks * 32);
    acc = __builtin_amdgcn_mfma_f32_16x16x32_bf16(a, b, acc, 0, 0, 0);
  }

  if ((l15 >> 2) == hi && (e0 + l15) < nE) {
    int j = l15 & 3;
    float v = acc[0];
    v = (j == 1) ? acc[1] : v;
    v = (j == 2) ? acc[2] : v;
    v = (j == 3) ? acc[3] : v;
    out[e.y] = v;
  }
}

// ---------------- launcher ----------------

extern "C" void kernel_launch(void* const* d_in, const int* in_sizes, int n_in,
                              void* d_out, int out_size, void* d_ws, size_t ws_size,
                              hipStream_t stream) {
  const float* features = (const float*)d_in[0];
  const int*   src      = (const int*)d_in[1];
  const int*   dst      = (const int*)d_in[2];
  const float* Wself1   = (const float*)d_in[3];
  const float* Wneigh1  = (const float*)d_in[4];
  const float* b1       = (const float*)d_in[5];
  const float* Wself2   = (const float*)d_in[6];
  const float* Wneigh2  = (const float*)d_in[7];
  const float* b2       = (const float*)d_in[8];
  float* score = (float*)d_out;

  const int nNodes = in_sizes[0] / NFEAT;       // 20000
  const int nE     = in_sizes[1];               // 320000
  const int mpad   = ((nNodes + 127) / 128) * 128;  // 20096

  char* ws = (char*)d_ws;
  size_t off = 0;
  auto alloc = [&](size_t bytes) { char* p = ws + off; off += (bytes + 255) & ~(size_t)255; return p; };
  bf16_t* Xcat1   = (bf16_t*)alloc((size_t)mpad * KDIM * 2);
  bf16_t* Xcat2   = (bf16_t*)alloc((size_t)mpad * KDIM * 2);
  bf16_t* H2      = (bf16_t*)alloc((size_t)mpad * NFEAT * 2);
  bf16_t* WT1     = (bf16_t*)alloc((size_t)NFEAT * KDIM * 2);
  bf16_t* WT2     = (bf16_t*)alloc((size_t)NFEAT * KDIM * 2);
  int*    deg     = (int*)alloc((size_t)mpad * 4);
  int*    offsets = (int*)alloc((size_t)mpad * 4);
  int*    cursor  = (int*)alloc((size_t)mpad * 4);
  float*  inv_deg = (float*)alloc((size_t)mpad * 4);
  int*    csr_src = (int*)alloc((size_t)nE * 4);
  int2*   epack   = (int2*)alloc((size_t)nE * 8);

  const int eb = (nE + 255) / 256;
  const int nb = (mpad + 255) / 256;     // 79 scan blocks

  // fused prep: 64 weight-transpose blocks + cast/deg-zero blocks
  k_prep<<<64 + (mpad * 64 + 255) / 256, 256, 0, stream>>>(features, Wself1, Wneigh1,
                                                           Wself2, Wneigh2, WT1, WT2,
                                                           Xcat1, deg, nNodes, mpad);

  // graph prep (count -> scan -> scatter)
  k_count_deg<<<eb, 256, 0, stream>>>(dst, deg, nE);
  k_scan<<<nb, 256, 0, stream>>>(deg, offsets, cursor, inv_deg, mpad, nb);
  k_scatter<<<eb, 256, 0, stream>>>(src, dst, cursor, csr_src, epack, nE);

  // layer 1
  k_agg<<<mpad / 8, 256, 0, stream>>>(Xcat1, Xcat1, csr_src, offsets, deg, inv_deg, KDIM, KDIM);
  dim3 ggrid(mpad / BM, NFEAT / BN);
  k_gemm<<<ggrid, 256, 0, stream>>>(Xcat1, WT1, b1, Xcat2, KDIM, 1);

  // layer 2
  k_agg<<<mpad / 8, 256, 0, stream>>>(Xcat2, Xcat2, csr_src, offsets, deg, inv_deg, KDIM, KDIM);
  k_gemm<<<ggrid, 256, 0, stream>>>(Xcat2, WT2, b2, H2, NFEAT, 0);

  // edge scores: one wave per 16 CSR slots
  const int nWaves = (nE + 15) / 16;
  k_edge_dot<<<(nWaves + 3) / 4, 256, 0, stream>>>(H2, epack, score, nE);
}